// Round 1
// baseline (933.941 us; speedup 1.0000x reference)
//
#include <hip/hip_runtime.h>
#include <math.h>
#include <stdint.h>

#define HID 256
#define HEADS 8
#define BN_EPS 1e-5f
#define NEG 0.2f

__device__ __forceinline__ float lrelu(float x) { return x > 0.f ? x : NEG * x; }
__device__ __forceinline__ float eluf(float x)  { return x > 0.f ? x : expm1f(x); }

// ---------------- CSR build ----------------

__global__ __launch_bounds__(256) void degree_kernel(const int* __restrict__ ei,
                                                     int* __restrict__ deg,
                                                     int E, int EE) {
    int e = blockIdx.x * 256 + threadIdx.x;
    if (e >= EE) return;
    int d = (e < E) ? ei[E + e] : (e - E);
    atomicAdd(&deg[d], 1);
}

__global__ __launch_bounds__(1024) void scan_kernel(const int* __restrict__ deg,
                                                    int* __restrict__ offs, int N) {
    __shared__ int part[1024];
    int t = threadIdx.x;
    int chunk = (N + 1023) >> 10;
    int c0 = t * chunk;
    int c1 = min(c0 + chunk, N);
    int s = 0;
    for (int j = c0; j < c1; ++j) s += deg[j];
    part[t] = s;
    __syncthreads();
    for (int d = 1; d < 1024; d <<= 1) {
        int vv = (t >= d) ? part[t - d] : 0;
        __syncthreads();
        part[t] += vv;
        __syncthreads();
    }
    int run = part[t] - s;  // exclusive prefix of this thread's chunk
    for (int j = c0; j < c1; ++j) { offs[j] = run; run += deg[j]; }
    if (t == 1023) offs[N] = part[1023];
}

__global__ __launch_bounds__(256) void scatter_kernel(const int* __restrict__ ei,
                                                      const int* __restrict__ offs,
                                                      int* __restrict__ cur,
                                                      int* __restrict__ csr_src,
                                                      int E, int EE) {
    int e = blockIdx.x * 256 + threadIdx.x;
    if (e >= EE) return;
    int s = (e < E) ? ei[e] : (e - E);
    int d = (e < E) ? ei[E + e] : (e - E);
    int pos = offs[d] + atomicAdd(&cur[d], 1);
    csr_src[pos] = s;
}

// ---------------- fused (BN[+bias+ELU]) -> GEMM -> attention dots ----------------
// MODE 0: t = bn(in)                      (layer 1 input)
// MODE 1: t = bn(elu(in + gbias))         (layer 2 input)
template <int K, int MODE>
__global__ __launch_bounds__(256) void gemm_s_kernel(
    const float* __restrict__ in, const float* __restrict__ W,
    const float* __restrict__ g, const float* __restrict__ b,
    const float* __restrict__ m, const float* __restrict__ v,
    const float* __restrict__ gbias,
    const float* __restrict__ a_src, const float* __restrict__ a_dst,
    float* __restrict__ h, float* __restrict__ s_src, float* __restrict__ s_dst,
    int N) {
    const int NPB = 16;
    __shared__ float rows[NPB][K];
    int tid = threadIdx.x;
    int base = blockIdx.x * NPB;

    for (int idx = tid; idx < NPB * K; idx += 256) {
        int r = idx / K, k = idx - r * K;
        int node = base + r;
        float val = 0.f;
        if (node < N) {
            val = in[(size_t)node * K + k];
            if (MODE == 1) {
                val += gbias[k];
                val = eluf(val);
            }
            float sc = g[k] * rsqrtf(v[k] + BN_EPS);
            val = (val - m[k]) * sc + b[k];
        }
        rows[r][k] = val;
    }
    __syncthreads();

    float acc[NPB];
#pragma unroll
    for (int i = 0; i < NPB; ++i) acc[i] = 0.f;

    for (int k = 0; k < K; k += 4) {
        float w0 = W[(size_t)(k + 0) * HID + tid];
        float w1 = W[(size_t)(k + 1) * HID + tid];
        float w2 = W[(size_t)(k + 2) * HID + tid];
        float w3 = W[(size_t)(k + 3) * HID + tid];
#pragma unroll
        for (int i = 0; i < NPB; ++i) {
            float4 r4 = *(const float4*)&rows[i][k];
            acc[i] = fmaf(r4.x, w0, acc[i]);
            acc[i] = fmaf(r4.y, w1, acc[i]);
            acc[i] = fmaf(r4.z, w2, acc[i]);
            acc[i] = fmaf(r4.w, w3, acc[i]);
        }
    }

#pragma unroll
    for (int i = 0; i < NPB; ++i) {
        int node = base + i;
        if (node < N) h[(size_t)node * HID + tid] = acc[i];
    }

    // attention dot products: col = tid = head*32 + d
    float as = a_src[tid], ad = a_dst[tid];
#pragma unroll
    for (int i = 0; i < NPB; ++i) {
        float vs = acc[i] * as;
        float vd = acc[i] * ad;
#pragma unroll
        for (int msk = 16; msk >= 1; msk >>= 1) {
            vs += __shfl_xor(vs, msk);
            vd += __shfl_xor(vd, msk);
        }
        int node = base + i;
        if ((tid & 31) == 0 && node < N) {
            s_src[node * HEADS + (tid >> 5)] = vs;
            s_dst[node * HEADS + (tid >> 5)] = vd;
        }
    }
}

// ---------------- per-dst-node segment softmax + aggregation ----------------
__global__ __launch_bounds__(256) void agg_kernel(
    const float* __restrict__ h, const float* __restrict__ s_src,
    const float* __restrict__ s_dst, const int* __restrict__ offs,
    const int* __restrict__ csr_src, float* __restrict__ outp, int N) {
    int vtx = blockIdx.x;
    int beg = offs[vtx], end = offs[vtx + 1];
    int deg = end - beg;
    __shared__ float mxs[HEADS], invs[HEADS], sdv_s[HEADS];
    int tid = threadIdx.x;
    int head = tid >> 5, el = tid & 31;
    if (tid < HEADS) sdv_s[tid] = s_dst[vtx * HEADS + tid];
    __syncthreads();
    float sdv = sdv_s[head];

    // pass 1: online max/sum per head, 32 edge-lanes per head
    float mval = -3.0e38f, sval = 0.f;
    for (int e = el; e < deg; e += 32) {
        int u = csr_src[beg + e];
        float sc = lrelu(s_src[u * HEADS + head] + sdv);
        float nm = fmaxf(mval, sc);
        sval = sval * __expf(mval - nm) + __expf(sc - nm);
        mval = nm;
    }
#pragma unroll
    for (int msk = 16; msk >= 1; msk >>= 1) {
        float om = __shfl_xor(mval, msk);
        float os = __shfl_xor(sval, msk);
        float nm = fmaxf(mval, om);
        sval = sval * __expf(mval - nm) + os * __expf(om - nm);
        mval = nm;
    }
    if (el == 0) { mxs[head] = mval; invs[head] = 1.f / sval; }
    __syncthreads();

    // pass 2: weighted aggregation, thread owns column tid
    float mh = mxs[head];
    float inv = invs[head];
    float acc = 0.f;
    for (int e = 0; e < deg; ++e) {
        int u = csr_src[beg + e];
        float sc = lrelu(s_src[u * HEADS + head] + sdv);
        float alpha = __expf(sc - mh) * inv;
        acc = fmaf(h[(size_t)u * HID + tid], alpha, acc);
    }
    outp[(size_t)vtx * HID + tid] = acc;
}

// ---------------- head: bn3(elu(agg2+b2)) + skip GEMM + p1/relu + p2 ----------------
__global__ __launch_bounds__(256) void final_kernel(
    const float* __restrict__ agg2, const float* __restrict__ x,
    const float* __restrict__ gbias,
    const float* __restrict__ g3, const float* __restrict__ b3,
    const float* __restrict__ m3, const float* __restrict__ v3,
    const float* __restrict__ skip_W, const float* __restrict__ skip_b,
    const float* __restrict__ p1_W, const float* __restrict__ p1_b,
    const float* __restrict__ p2_W, const float* __restrict__ p2_b,
    float* __restrict__ outp, int N) {
    const int NPB = 32;
    __shared__ float f3[NPB][HID + 1];
    __shared__ float xr[NPB][64];
    int tid = threadIdx.x;
    int base = blockIdx.x * NPB;

    for (int idx = tid; idx < NPB * 64; idx += 256) {
        int r = idx >> 6, k = idx & 63;
        int node = base + r;
        xr[r][k] = (node < N) ? x[(size_t)node * 64 + k] : 0.f;
    }
    __syncthreads();

    // skip GEMM: stream skip_W once, 32 node accumulators per thread (col = tid)
    float acc[NPB];
#pragma unroll
    for (int i = 0; i < NPB; ++i) acc[i] = 0.f;
    for (int k = 0; k < 64; ++k) {
        float wv = skip_W[(size_t)k * HID + tid];
#pragma unroll
        for (int i = 0; i < NPB; ++i) acc[i] = fmaf(xr[i][k], wv, acc[i]);
    }

    float sc3 = g3[tid] * rsqrtf(v3[tid] + BN_EPS);
    float bb = gbias[tid], mm = m3[tid], b3v = b3[tid], sb = skip_b[tid];
    for (int i = 0; i < NPB; ++i) {
        int node = base + i;
        float t = 0.f;
        if (node < N) t = agg2[(size_t)node * HID + tid];
        t += bb;
        t = eluf(t);
        t = (t - mm) * sc3 + b3v;
        f3[i][tid] = t + acc[i] + sb;
    }
    __syncthreads();

    // p1 (256->32) + relu + p2 (32->1): 8 threads per node, 4 j's each
    int node = tid >> 3, r = tid & 7;
    float po = 0.f;
#pragma unroll
    for (int q = 0; q < 4; ++q) {
        int j = q * 8 + r;
        float z = p1_b[j];
        for (int c = 0; c < HID; ++c) z = fmaf(f3[node][c], p1_W[c * 32 + j], z);
        z = fmaxf(z, 0.f);
        po = fmaf(z, p2_W[j], po);
    }
#pragma unroll
    for (int msk = 4; msk >= 1; msk >>= 1) po += __shfl_xor(po, msk);
    int gn = base + node;
    if (r == 0 && gn < N) outp[gn] = po + p2_b[0];
}

// ---------------- launch ----------------

extern "C" void kernel_launch(void* const* d_in, const int* in_sizes, int n_in,
                              void* d_out, int out_size, void* d_ws, size_t ws_size,
                              hipStream_t stream) {
    const float* x      = (const float*)d_in[0];
    const int*   ei     = (const int*)  d_in[1];
    const float* bn1_g  = (const float*)d_in[2];
    const float* bn1_b  = (const float*)d_in[3];
    const float* bn1_m  = (const float*)d_in[4];
    const float* bn1_v  = (const float*)d_in[5];
    const float* W1     = (const float*)d_in[6];
    const float* a1_src = (const float*)d_in[7];
    const float* a1_dst = (const float*)d_in[8];
    const float* b1     = (const float*)d_in[9];
    const float* bn2_g  = (const float*)d_in[10];
    const float* bn2_b  = (const float*)d_in[11];
    const float* bn2_m  = (const float*)d_in[12];
    const float* bn2_v  = (const float*)d_in[13];
    const float* W2     = (const float*)d_in[14];
    const float* a2_src = (const float*)d_in[15];
    const float* a2_dst = (const float*)d_in[16];
    const float* b2     = (const float*)d_in[17];
    const float* bn3_g  = (const float*)d_in[18];
    const float* bn3_b  = (const float*)d_in[19];
    const float* bn3_m  = (const float*)d_in[20];
    const float* bn3_v  = (const float*)d_in[21];
    const float* skip_W = (const float*)d_in[22];
    const float* skip_b = (const float*)d_in[23];
    const float* p1_W   = (const float*)d_in[24];
    const float* p1_b   = (const float*)d_in[25];
    const float* p2_W   = (const float*)d_in[26];
    const float* p2_b   = (const float*)d_in[27];

    int N = in_sizes[0] / 64;
    int E = in_sizes[1] / 2;
    int EE = E + N;  // + self loops

    uintptr_t w = (uintptr_t)d_ws;
    auto carve = [&](size_t bytes) -> void* {
        uintptr_t p = w;
        w += (bytes + 255) & ~(size_t)255;
        return (void*)p;
    };
    int*   deg  = (int*)carve((size_t)N * 4);
    int*   cur  = (int*)carve((size_t)N * 4);
    int*   offs = (int*)carve(((size_t)N + 1) * 4);
    int*   csr  = (int*)carve((size_t)EE * 4);
    float* ssrc = (float*)carve((size_t)N * HEADS * 4);
    float* sdst = (float*)carve((size_t)N * HEADS * 4);
    float* bufA = (float*)carve((size_t)N * HID * 4);
    float* bufB = (float*)carve((size_t)N * HID * 4);

    hipMemsetAsync(deg, 0, (size_t)N * 4, stream);
    hipMemsetAsync(cur, 0, (size_t)N * 4, stream);

    int eblk = (EE + 255) / 256;
    degree_kernel<<<eblk, 256, 0, stream>>>(ei, deg, E, EE);
    scan_kernel<<<1, 1024, 0, stream>>>(deg, offs, N);
    scatter_kernel<<<eblk, 256, 0, stream>>>(ei, offs, cur, csr, E, EE);

    int gblk = (N + 15) / 16;
    // layer 1: h1 = bn1(x) @ W1 ; s1
    gemm_s_kernel<64, 0><<<gblk, 256, 0, stream>>>(
        x, W1, bn1_g, bn1_b, bn1_m, bn1_v, nullptr, a1_src, a1_dst,
        bufA, ssrc, sdst, N);
    agg_kernel<<<N, 256, 0, stream>>>(bufA, ssrc, sdst, offs, csr, bufB, N);

    // layer 2: h2 = bn2(elu(agg1 + b1)) @ W2 ; s2
    gemm_s_kernel<HID, 1><<<gblk, 256, 0, stream>>>(
        bufB, W2, bn2_g, bn2_b, bn2_m, bn2_v, b1, a2_src, a2_dst,
        bufA, ssrc, sdst, N);
    agg_kernel<<<N, 256, 0, stream>>>(bufA, ssrc, sdst, offs, csr, bufB, N);

    // head
    int fblk = (N + 31) / 32;
    final_kernel<<<fblk, 256, 0, stream>>>(
        bufB, x, b2, bn3_g, bn3_b, bn3_m, bn3_v, skip_W, skip_b,
        p1_W, p1_b, p2_W, p2_b, (float*)d_out, N);
}